// Round 6
// baseline (350.409 us; speedup 1.0000x reference)
//
#include <hip/hip_runtime.h>

typedef float __attribute__((ext_vector_type(4))) f32x4;
typedef unsigned int __attribute__((ext_vector_type(2))) u32x2;

#define M_DIM 65536
#define N_DIM 1024
#define K_DIM 1024

#define BM 128
#define BN 128
#define BK 64

// pack 4 floats -> 4 fp8 e4m3 bytes (RNE, OCP on gfx950)
__device__ inline unsigned int cvt4(float f0, float f1, float f2, float f3) {
    int r = __builtin_amdgcn_cvt_pk_fp8_f32(f0, f1, 0, false);   // bytes 0,1
    r = __builtin_amdgcn_cvt_pk_fp8_f32(f2, f3, r, true);        // bytes 2,3
    return (unsigned int)r;
}

// Fully fused, zero-workspace kernel:
//   C[M,N] = f32( fp16_round( (fp8(A) @ fp8(W)) * scale_b[n] ) )
// A arrives as f32 (harness upcasts the reference's f16 input).
// 128x128 tile, BK=64, 4 waves (2x2), 16x16x32 fp8 MFMA.
// A rows in LDS use an 8B-granule XOR(row&6) swizzle (write-side + read-side).
// LDS B: [g][n][8], content sB[g*1024+n*8+j] = fp8(W[kt*64+g*8+j][n0+n]).
__global__ __launch_bounds__(256) void gemm_fused_kernel(const float* __restrict__ A,
                                                         const float* __restrict__ W,
                                                         const float* __restrict__ scale_b,
                                                         float* __restrict__ out) {
    __shared__ __attribute__((aligned(16))) unsigned char sA[BM * BK];  // 8 KB
    __shared__ __attribute__((aligned(16))) unsigned char sB[BK * BN];  // 8 KB

    const int tid = threadIdx.x;
    const int l = tid & 63;
    const int wid = tid >> 6;        // 0..3
    const int lr = l & 15;           // fragment row/col lane part
    const int lg = l >> 4;           // k-group lane part (0..3)
    const int wr = wid >> 1;         // wave row (0..1)
    const int wc = wid & 1;          // wave col (0..1)
    const int n0 = blockIdx.x * BN;  // n fastest: 8 consecutive blocks share one A-panel
    const int m0 = blockIdx.y * BM;

    f32x4 acc[4][4];
#pragma unroll
    for (int i = 0; i < 4; ++i)
#pragma unroll
        for (int j = 0; j < 4; ++j) acc[i][j] = (f32x4)0.0f;

    // A staging: thread covers (row = o*32 + (tid>>3), granule g = tid&7)
    const int a_g = tid & 7;
    const int a_rb = tid >> 3;       // 0..31
    const int aswz = lr & 6;         // read-side swizzle key

    for (int kt = 0; kt < K_DIM / BK; ++kt) {
        const int k0 = kt * BK;

        // ---- stage A: load f32x8, quantize to fp8 (RNE), swizzled LDS write ----
#pragma unroll
        for (int o = 0; o < 4; ++o) {
            const int row = o * 32 + a_rb;                       // 0..127
            const float* ap = A + (size_t)(m0 + row) * K_DIM + k0 + a_g * 8;
            const f32x4 v0 = *(const f32x4*)ap;
            const f32x4 v1 = *(const f32x4*)(ap + 4);
            u32x2 r;
            r.x = cvt4(v0[0], v0[1], v0[2], v0[3]);
            r.y = cvt4(v1[0], v1[1], v1[2], v1[3]);
            *(u32x2*)(sA + row * 64 + ((a_g ^ (row & 6)) * 8)) = r;
        }

        // ---- stage B: load W f32 (L2-resident), quantize, LDS write ----
#pragma unroll
        for (int o = 0; o < 4; ++o) {
            const int e = o * 256 + tid;
            const int g = e >> 7;                                 // k-group 0..7
            const int n = e & 127;                                // col 0..127
            const float* wp = W + (size_t)(k0 + g * 8) * N_DIM + n0 + n;
            float f[8];
#pragma unroll
            for (int j = 0; j < 8; ++j) f[j] = wp[(size_t)j * N_DIM];
            u32x2 r;
            r.x = cvt4(f[0], f[1], f[2], f[3]);
            r.y = cvt4(f[4], f[5], f[6], f[7]);
            *(u32x2*)(sB + g * 1024 + n * 8) = r;
        }
        __syncthreads();

        // ---- compute: 2 k-halves x 4x4 fragments ----
#pragma unroll
        for (int kk = 0; kk < 2; ++kk) {
            long long af[4], bf[4];
            const int gread = kk * 4 + lg;
#pragma unroll
            for (int mi = 0; mi < 4; ++mi) {
                const int m = wr * 64 + mi * 16 + lr;
                af[mi] = *(const long long*)(sA + m * 64 + ((gread ^ aswz) * 8));
            }
#pragma unroll
            for (int nj = 0; nj < 4; ++nj) {
                const int n = wc * 64 + nj * 16 + lr;
                bf[nj] = *(const long long*)(sB + gread * 1024 + n * 8);
            }
#pragma unroll
            for (int mi = 0; mi < 4; ++mi)
#pragma unroll
                for (int nj = 0; nj < 4; ++nj)
                    acc[mi][nj] = __builtin_amdgcn_mfma_f32_16x16x32_fp8_fp8(
                        af[mi], bf[nj], acc[mi][nj], 0, 0, 0);
        }
        __syncthreads();  // all reads done before next-step overwrite
    }

    // ---- epilogue: scale, round through fp16, store f32 ----
    // C/D layout: col = lane&15, row = (lane>>4)*4 + reg
#pragma unroll
    for (int nj = 0; nj < 4; ++nj) {
        const int col = n0 + wc * 64 + nj * 16 + lr;
        const float sc = scale_b[col];
#pragma unroll
        for (int mi = 0; mi < 4; ++mi) {
            const int row = m0 + wr * 64 + mi * 16 + lg * 4;
#pragma unroll
            for (int r = 0; r < 4; ++r) {
                const float v = acc[mi][nj][r] * sc;
                out[(size_t)(row + r) * N_DIM + col] = (float)(_Float16)v;
            }
        }
    }
}

extern "C" void kernel_launch(void* const* d_in, const int* in_sizes, int n_in,
                              void* d_out, int out_size, void* d_ws, size_t ws_size,
                              hipStream_t stream) {
    (void)out_size; (void)d_ws; (void)ws_size;
    // Defensive runtime mapping by element count (all three are distinct):
    const void* pA = d_in[0];
    const void* pW = (n_in > 1) ? d_in[1] : d_in[0];
    const void* pS = (n_in > 2) ? d_in[2] : d_in[0];
    for (int i = 0; i < n_in && i < 3; ++i) {
        if (in_sizes[i] == M_DIM * K_DIM) pA = d_in[i];
        else if (in_sizes[i] == K_DIM * N_DIM) pW = d_in[i];
        else if (in_sizes[i] == N_DIM) pS = d_in[i];
    }
    const float* A = (const float*)pA;
    const float* W = (const float*)pW;
    const float* sb = (const float*)pS;
    float* out = (float*)d_out;

    gemm_fused_kernel<<<dim3(N_DIM / BN, M_DIM / BM), 256, 0, stream>>>(A, W, sb, out);
}

// Round 7
// 250.888 us; speedup vs baseline: 1.3967x; 1.3967x over previous
//
#include <hip/hip_runtime.h>

#define AS1 __attribute__((address_space(1)))
#define AS3 __attribute__((address_space(3)))

typedef float __attribute__((ext_vector_type(4))) f32x4;
typedef unsigned int __attribute__((ext_vector_type(2))) u32x2;

#define M_DIM 65536
#define N_DIM 1024
#define K_DIM 1024

#define BM 128
#define BN 128
#define BK 64

#define WS_NEEDED ((size_t)M_DIM * K_DIM + (size_t)K_DIM * N_DIM)  // A8 64MB + W8 1MB

// pack 4 floats -> 4 fp8 e4m3 bytes (RNE, OCP on gfx950)
__device__ inline unsigned int cvt4(float f0, float f1, float f2, float f3) {
    int r = __builtin_amdgcn_cvt_pk_fp8_f32(f0, f1, 0, false);   // bytes 0,1
    r = __builtin_amdgcn_cvt_pk_fp8_f32(f2, f3, r, true);        // bytes 2,3
    return (unsigned int)r;
}

// ---------------- pass 1a: A f32 -> fp8 row-major ----------------
__global__ __launch_bounds__(256) void quant_a_kernel(const float* __restrict__ in,
                                                      unsigned char* __restrict__ out) {
    const int total8 = (M_DIM * K_DIM) / 8;          // 8388608
    const int stride = 2048 * 256;
    for (int i = blockIdx.x * 256 + threadIdx.x; i < total8; i += stride) {
        const float* p = in + (size_t)i * 8;
        const f32x4 v0 = *(const f32x4*)p;
        const f32x4 v1 = *(const f32x4*)(p + 4);
        u32x2 r;
        r.x = cvt4(v0[0], v0[1], v0[2], v0[3]);
        r.y = cvt4(v1[0], v1[1], v1[2], v1[3]);
        ((u32x2*)out)[i] = r;
    }
}

// ---------------- pass 1b: W f32 -> fp8 packed [K/8][N][8] ----------------
// out[(gt*N + n)*8 + j] = fp8(W[gt*8 + j][n])
__global__ __launch_bounds__(256) void quant_w_kernel(const float* __restrict__ w,
                                                      unsigned char* __restrict__ out) {
    const int idx = blockIdx.x * 256 + threadIdx.x;  // 0..131071
    const int gt = idx >> 10, n = idx & 1023;
    const float* wp = w + (size_t)(gt * 8) * N_DIM + n;
    float f[8];
#pragma unroll
    for (int j = 0; j < 8; ++j) f[j] = wp[(size_t)j * N_DIM];
    u32x2 r;
    r.x = cvt4(f[0], f[1], f[2], f[3]);
    r.y = cvt4(f[4], f[5], f[6], f[7]);
    ((u32x2*)out)[idx] = r;
}

// ---------------- pass 2: fp8 GEMM, global_load_lds staging ----------------
// C[M,N] = f32(fp16_round(A8 @ W8 * scale_b)). 128x128 tile, BK=64, 4 waves.
// A LDS rows 64B with 8B-granule XOR(row&6) swizzle (applied on the global src).
// B LDS [g][n][8] linear (source contiguous). XCD-aware block swizzle.
__global__ __launch_bounds__(256) void gemm_fp8_kernel(const unsigned char* __restrict__ A8,
                                                       const unsigned char* __restrict__ B8,
                                                       const float* __restrict__ scale_b,
                                                       float* __restrict__ out) {
    __shared__ __attribute__((aligned(16))) unsigned char sA[BM * BK];  // 8 KB
    __shared__ __attribute__((aligned(16))) unsigned char sB[BK * BN];  // 8 KB

    const int tid = threadIdx.x;
    const int l = tid & 63;
    const int wid = tid >> 6;        // 0..3
    const int lr = l & 15;
    const int lg = l >> 4;
    const int wr = wid >> 1;
    const int wc = wid & 1;

    // XCD swizzle: 4096 blocks, XCD = b&7 (round-robin). Give each XCD 64
    // consecutive m-panels; within, the 8 n-tiles of a panel run back-to-back.
    const int b = blockIdx.x;
    const int local = b >> 3;                         // 0..511
    const int m_idx = (b & 7) * 64 + (local >> 3);    // 0..511
    const int n_idx = local & 7;                      // 0..7
    const int m0 = m_idx * BM;
    const int n0 = n_idx * BN;

    f32x4 acc[4][4];
#pragma unroll
    for (int i = 0; i < 4; ++i)
#pragma unroll
        for (int j = 0; j < 4; ++j) acc[i][j] = (f32x4)0.0f;

    // A staging lane constants (chunk i: rows i*16..i*16+15, 64B each, linear LDS)
    const int a_rl = l >> 2;                // row within chunk 0..15
    const int a_u = (l & 3) * 2;            // 16B unit -> granule pair base
    const int aswz = lr & 6;                // read-side swizzle key

    for (int kt = 0; kt < K_DIM / BK; ++kt) {
        const int k0 = kt * BK;
        // ---- stage A: 8 chunks of 1KB; this wave does 2 ----
#pragma unroll
        for (int c = 0; c < 2; ++c) {
            const int i = wid * 2 + c;
            const int row = i * 16 + a_rl;
            const unsigned char* src =
                A8 + (size_t)(m0 + row) * K_DIM + k0 + ((a_u ^ (row & 6)) * 8);
            __builtin_amdgcn_global_load_lds((const AS1 void*)src,
                                             (AS3 void*)(sA + i * 1024), 16, 0, 0);
        }
        // ---- stage B: 8 chunks of 1KB, fully contiguous source ----
#pragma unroll
        for (int c = 0; c < 2; ++c) {
            const int g = wid * 2 + c;
            const unsigned char* src =
                B8 + ((size_t)(kt * 8 + g) * N_DIM + n0) * 8 + l * 16;
            __builtin_amdgcn_global_load_lds((const AS1 void*)src,
                                             (AS3 void*)(sB + g * 1024), 16, 0, 0);
        }
        __syncthreads();  // drains vmcnt + lgkmcnt

        // ---- compute: 2 k-halves x 4x4 fragments ----
#pragma unroll
        for (int kk = 0; kk < 2; ++kk) {
            long long af[4], bf[4];
            const int gread = kk * 4 + lg;
#pragma unroll
            for (int mi = 0; mi < 4; ++mi) {
                const int m = wr * 64 + mi * 16 + lr;
                af[mi] = *(const long long*)(sA + m * 64 + ((gread ^ aswz) * 8));
            }
#pragma unroll
            for (int nj = 0; nj < 4; ++nj) {
                const int n = wc * 64 + nj * 16 + lr;
                bf[nj] = *(const long long*)(sB + gread * 1024 + n * 8);
            }
#pragma unroll
            for (int mi = 0; mi < 4; ++mi)
#pragma unroll
                for (int nj = 0; nj < 4; ++nj)
                    acc[mi][nj] = __builtin_amdgcn_mfma_f32_16x16x32_fp8_fp8(
                        af[mi], bf[nj], acc[mi][nj], 0, 0, 0);
        }
        __syncthreads();
    }

    // ---- epilogue: scale, round through fp16, store f32 ----
#pragma unroll
    for (int nj = 0; nj < 4; ++nj) {
        const int col = n0 + wc * 64 + nj * 16 + lr;
        const float sc = scale_b[col];
#pragma unroll
        for (int mi = 0; mi < 4; ++mi) {
            const int row = m0 + wr * 64 + mi * 16 + lg * 4;
#pragma unroll
            for (int r = 0; r < 4; ++r) {
                const float v = acc[mi][nj][r] * sc;
                out[(size_t)(row + r) * N_DIM + col] = (float)(_Float16)v;
            }
        }
    }
}

// ---------------- fallback: round-6 fused kernel (passing, 350 us) ----------------
__global__ __launch_bounds__(256) void gemm_fused_kernel(const float* __restrict__ A,
                                                         const float* __restrict__ W,
                                                         const float* __restrict__ scale_b,
                                                         float* __restrict__ out) {
    __shared__ __attribute__((aligned(16))) unsigned char sA[BM * BK];
    __shared__ __attribute__((aligned(16))) unsigned char sB[BK * BN];

    const int tid = threadIdx.x;
    const int l = tid & 63;
    const int wid = tid >> 6;
    const int lr = l & 15;
    const int lg = l >> 4;
    const int wr = wid >> 1;
    const int wc = wid & 1;
    const int n0 = blockIdx.x * BN;
    const int m0 = blockIdx.y * BM;

    f32x4 acc[4][4];
#pragma unroll
    for (int i = 0; i < 4; ++i)
#pragma unroll
        for (int j = 0; j < 4; ++j) acc[i][j] = (f32x4)0.0f;

    const int a_g = tid & 7;
    const int a_rb = tid >> 3;
    const int aswz = lr & 6;

    for (int kt = 0; kt < K_DIM / BK; ++kt) {
        const int k0 = kt * BK;
#pragma unroll
        for (int o = 0; o < 4; ++o) {
            const int row = o * 32 + a_rb;
            const float* ap = A + (size_t)(m0 + row) * K_DIM + k0 + a_g * 8;
            const f32x4 v0 = *(const f32x4*)ap;
            const f32x4 v1 = *(const f32x4*)(ap + 4);
            u32x2 r;
            r.x = cvt4(v0[0], v0[1], v0[2], v0[3]);
            r.y = cvt4(v1[0], v1[1], v1[2], v1[3]);
            *(u32x2*)(sA + row * 64 + ((a_g ^ (row & 6)) * 8)) = r;
        }
#pragma unroll
        for (int o = 0; o < 4; ++o) {
            const int e = o * 256 + tid;
            const int g = e >> 7;
            const int n = e & 127;
            const float* wp = W + (size_t)(k0 + g * 8) * N_DIM + n0 + n;
            float f[8];
#pragma unroll
            for (int j = 0; j < 8; ++j) f[j] = wp[(size_t)j * N_DIM];
            u32x2 r;
            r.x = cvt4(f[0], f[1], f[2], f[3]);
            r.y = cvt4(f[4], f[5], f[6], f[7]);
            *(u32x2*)(sB + g * 1024 + n * 8) = r;
        }
        __syncthreads();

#pragma unroll
        for (int kk = 0; kk < 2; ++kk) {
            long long af[4], bf[4];
            const int gread = kk * 4 + lg;
#pragma unroll
            for (int mi = 0; mi < 4; ++mi) {
                const int m = wr * 64 + mi * 16 + lr;
                af[mi] = *(const long long*)(sA + m * 64 + ((gread ^ aswz) * 8));
            }
#pragma unroll
            for (int nj = 0; nj < 4; ++nj) {
                const int n = wc * 64 + nj * 16 + lr;
                bf[nj] = *(const long long*)(sB + gread * 1024 + n * 8);
            }
#pragma unroll
            for (int mi = 0; mi < 4; ++mi)
#pragma unroll
                for (int nj = 0; nj < 4; ++nj)
                    acc[mi][nj] = __builtin_amdgcn_mfma_f32_16x16x32_fp8_fp8(
                        af[mi], bf[nj], acc[mi][nj], 0, 0, 0);
        }
        __syncthreads();
    }

#pragma unroll
    for (int nj = 0; nj < 4; ++nj) {
        const int col = n0 + wc * 64 + nj * 16 + lr;
        const float sc = scale_b[col];
#pragma unroll
        for (int mi = 0; mi < 4; ++mi) {
            const int row = m0 + wr * 64 + mi * 16 + lg * 4;
#pragma unroll
            for (int r = 0; r < 4; ++r) {
                const float v = acc[mi][nj][r] * sc;
                out[(size_t)(row + r) * N_DIM + col] = (float)(_Float16)v;
            }
        }
    }
}

extern "C" void kernel_launch(void* const* d_in, const int* in_sizes, int n_in,
                              void* d_out, int out_size, void* d_ws, size_t ws_size,
                              hipStream_t stream) {
    (void)out_size;
    const void* pA = d_in[0];
    const void* pW = (n_in > 1) ? d_in[1] : d_in[0];
    const void* pS = (n_in > 2) ? d_in[2] : d_in[0];
    for (int i = 0; i < n_in && i < 3; ++i) {
        if (in_sizes[i] == M_DIM * K_DIM) pA = d_in[i];
        else if (in_sizes[i] == K_DIM * N_DIM) pW = d_in[i];
        else if (in_sizes[i] == N_DIM) pS = d_in[i];
    }
    const float* A = (const float*)pA;
    const float* W = (const float*)pW;
    const float* sb = (const float*)pS;
    float* out = (float*)d_out;

    if (ws_size >= WS_NEEDED && d_ws != nullptr) {
        unsigned char* A8 = (unsigned char*)d_ws;
        unsigned char* W8 = A8 + (size_t)M_DIM * K_DIM;
        quant_a_kernel<<<2048, 256, 0, stream>>>(A, A8);
        quant_w_kernel<<<512, 256, 0, stream>>>(W, W8);
        gemm_fp8_kernel<<<(M_DIM / BM) * (N_DIM / BN), 256, 0, stream>>>(A8, W8, sb, out);
    } else {
        gemm_fused_kernel<<<dim3(N_DIM / BN, M_DIM / BM), 256, 0, stream>>>(A, W, sb, out);
    }
}

// Round 8
// 212.324 us; speedup vs baseline: 1.6504x; 1.1816x over previous
//
#include <hip/hip_runtime.h>

#define AS1 __attribute__((address_space(1)))
#define AS3 __attribute__((address_space(3)))

typedef float __attribute__((ext_vector_type(4))) f32x4;
typedef unsigned int __attribute__((ext_vector_type(2))) u32x2;
typedef int __attribute__((ext_vector_type(4))) i32x4;
typedef int __attribute__((ext_vector_type(8))) i32x8;

#define M_DIM 65536
#define N_DIM 1024
#define K_DIM 1024

#define BM 128
#define BN 128
#define BK 128

#define WS_NEEDED ((size_t)M_DIM * K_DIM + (size_t)K_DIM * N_DIM)  // A8 64MB + W8 1MB
#define SCALE_ONE 0x7F7F7F7F  // e8m0 127 = 2^0 in every byte -> scale 1.0 for any opsel

// pack 4 floats -> 4 fp8 e4m3 bytes (RNE, OCP on gfx950)
__device__ inline unsigned int cvt4(float f0, float f1, float f2, float f3) {
    int r = __builtin_amdgcn_cvt_pk_fp8_f32(f0, f1, 0, false);   // bytes 0,1
    r = __builtin_amdgcn_cvt_pk_fp8_f32(f2, f3, r, true);        // bytes 2,3
    return (unsigned int)r;
}

// ---------------- pass 1a: A f32 -> fp8 row-major ----------------
__global__ __launch_bounds__(256) void quant_a_kernel(const float* __restrict__ in,
                                                      unsigned char* __restrict__ out) {
    const int total8 = (M_DIM * K_DIM) / 8;          // 8388608
    const int stride = 2048 * 256;
    for (int i = blockIdx.x * 256 + threadIdx.x; i < total8; i += stride) {
        const float* p = in + (size_t)i * 8;
        const f32x4 v0 = *(const f32x4*)p;
        const f32x4 v1 = *(const f32x4*)(p + 4);
        u32x2 r;
        r.x = cvt4(v0[0], v0[1], v0[2], v0[3]);
        r.y = cvt4(v1[0], v1[1], v1[2], v1[3]);
        ((u32x2*)out)[i] = r;
    }
}

// ---------------- pass 1b: W f32 -> fp8 packed [K/16][N][16] ----------------
// out[(t*N + n)*16 + s] = fp8(W[t*16 + s][n])
__global__ __launch_bounds__(256) void quant_w_kernel(const float* __restrict__ w,
                                                      unsigned char* __restrict__ out) {
    const int idx = blockIdx.x * 256 + threadIdx.x;  // 0..65535
    const int t = idx >> 10, n = idx & 1023;
    const float* wp = w + (size_t)(t * 16) * N_DIM + n;
    unsigned int r[4];
#pragma unroll
    for (int q = 0; q < 4; ++q) {
        float f0 = wp[(size_t)(q * 4 + 0) * N_DIM];
        float f1 = wp[(size_t)(q * 4 + 1) * N_DIM];
        float f2 = wp[(size_t)(q * 4 + 2) * N_DIM];
        float f3 = wp[(size_t)(q * 4 + 3) * N_DIM];
        r[q] = cvt4(f0, f1, f2, f3);
    }
    i32x4 v; v.x = (int)r[0]; v.y = (int)r[1]; v.z = (int)r[2]; v.w = (int)r[3];
    ((i32x4*)out)[idx] = v;
}

// ---------------- pass 2: MX-fp8 GEMM (scale=1.0), global_load_lds staging ----------------
// C[M,N] = f32(fp16_round(A8 @ W8 * scale_b)). 128x128 tile, BK=128, 4 waves (2x2).
// MFMA: mfma_scale_f32_16x16x128_f8f6f4, fp8/fp8, scales = 1.0 -> identical math to
// non-scaled fp8 at 2x rate. One MFMA per fragment pair per K-step.
// LDS A: rows of 128B, 16B-unit XOR(row&7) swizzle (applied on the global source).
// LDS B: [t=k/16][n][16] linear (source contiguous after packing).
__global__ __launch_bounds__(256) void gemm_fp8_kernel(const unsigned char* __restrict__ A8,
                                                       const unsigned char* __restrict__ B8,
                                                       const float* __restrict__ scale_b,
                                                       float* __restrict__ out) {
    __shared__ __attribute__((aligned(16))) unsigned char sA[BM * BK];  // 16 KB
    __shared__ __attribute__((aligned(16))) unsigned char sB[BK * BN];  // 16 KB

    const int tid = threadIdx.x;
    const int l = tid & 63;
    const int wid = tid >> 6;        // 0..3
    const int lr = l & 15;
    const int lg = l >> 4;           // k-quarter (32 elements each)
    const int wr = wid >> 1;
    const int wc = wid & 1;

    // XCD swizzle: 4096 blocks, XCD = b&7. Each XCD gets 64 consecutive m-panels;
    // within a panel the 8 n-tiles run back-to-back (A8-panel L2-resident).
    const int b = blockIdx.x;
    const int local = b >> 3;                         // 0..511
    const int m_idx = (b & 7) * 64 + (local >> 3);    // 0..511
    const int n_idx = local & 7;                      // 0..7
    const int m0 = m_idx * BM;
    const int n0 = n_idx * BN;

    f32x4 acc[4][4];
#pragma unroll
    for (int i = 0; i < 4; ++i)
#pragma unroll
        for (int j = 0; j < 4; ++j) acc[i][j] = (f32x4)0.0f;

    // A staging lane constants: chunk = 8 rows x 128B; lane l -> row l>>3, unit l&7
    const int a_rl = l >> 3;                 // row within chunk 0..7
    const int a_u = l & 7;                   // dest 16B unit

    for (int kt = 0; kt < K_DIM / BK; ++kt) {
        const int k0 = kt * BK;
        // ---- stage A: 16 chunks of 1KB; this wave does 4 ----
#pragma unroll
        for (int c = 0; c < 4; ++c) {
            const int i = wid * 4 + c;
            const int row = i * 8 + a_rl;             // 0..127
            const unsigned char* src =
                A8 + (size_t)(m0 + row) * K_DIM + k0 + ((a_u ^ (row & 7)) * 16);
            __builtin_amdgcn_global_load_lds((const AS1 void*)src,
                                             (AS3 void*)(sA + i * 1024), 16, 0, 0);
        }
        // ---- stage B: 16 chunks of 1KB, fully contiguous source ----
#pragma unroll
        for (int c = 0; c < 4; ++c) {
            const int idx = wid * 4 + c;              // 0..15
            const int tt = idx >> 1, hf = idx & 1;
            const unsigned char* src =
                B8 + ((size_t)(kt * 8 + tt) * N_DIM + n0 + hf * 64) * 16 + l * 16;
            __builtin_amdgcn_global_load_lds((const AS1 void*)src,
                                             (AS3 void*)(sB + tt * 2048 + hf * 1024), 16, 0, 0);
        }
        __syncthreads();  // drains vmcnt + lgkmcnt

        // ---- compute: 4x4 fragments, one K=128 MFMA each ----
        i32x8 bf[4];
#pragma unroll
        for (int nj = 0; nj < 4; ++nj) {
            const int n = wc * 64 + nj * 16 + lr;
            const i32x4 b0 = *(const i32x4*)(sB + (lg * 2 + 0) * 2048 + n * 16);
            const i32x4 b1 = *(const i32x4*)(sB + (lg * 2 + 1) * 2048 + n * 16);
            bf[nj] = __builtin_shufflevector(b0, b1, 0, 1, 2, 3, 4, 5, 6, 7);
        }
#pragma unroll
        for (int mi = 0; mi < 4; ++mi) {
            const int r = wr * 64 + mi * 16 + lr;
            const i32x4 a0 = *(const i32x4*)(sA + r * 128 + (((2 * lg + 0) ^ (r & 7)) * 16));
            const i32x4 a1 = *(const i32x4*)(sA + r * 128 + (((2 * lg + 1) ^ (r & 7)) * 16));
            const i32x8 af = __builtin_shufflevector(a0, a1, 0, 1, 2, 3, 4, 5, 6, 7);
#pragma unroll
            for (int nj = 0; nj < 4; ++nj)
                acc[mi][nj] = __builtin_amdgcn_mfma_scale_f32_16x16x128_f8f6f4(
                    af, bf[nj], acc[mi][nj], 0, 0,        // cbsz=fp8, blgp=fp8
                    0, SCALE_ONE, 0, SCALE_ONE);          // opsel/scale A, opsel/scale B
        }
        __syncthreads();
    }

    // ---- epilogue: scale, round through fp16, store f32 ----
    // C/D layout (shape-determined): col = lane&15, row = (lane>>4)*4 + reg
#pragma unroll
    for (int nj = 0; nj < 4; ++nj) {
        const int col = n0 + wc * 64 + nj * 16 + lr;
        const float sc = scale_b[col];
#pragma unroll
        for (int mi = 0; mi < 4; ++mi) {
            const int row = m0 + wr * 64 + mi * 16 + lg * 4;
#pragma unroll
            for (int r = 0; r < 4; ++r) {
                const float v = acc[mi][nj][r] * sc;
                out[(size_t)(row + r) * N_DIM + col] = (float)(_Float16)v;
            }
        }
    }
}

// ---------------- fallback: round-6 fused kernel (passing, 350 us) ----------------
__global__ __launch_bounds__(256) void gemm_fused_kernel(const float* __restrict__ A,
                                                         const float* __restrict__ W,
                                                         const float* __restrict__ scale_b,
                                                         float* __restrict__ out) {
    __shared__ __attribute__((aligned(16))) unsigned char sA[128 * 64];
    __shared__ __attribute__((aligned(16))) unsigned char sB[64 * 128];

    const int tid = threadIdx.x;
    const int l = tid & 63;
    const int wid = tid >> 6;
    const int lr = l & 15;
    const int lg = l >> 4;
    const int wr = wid >> 1;
    const int wc = wid & 1;
    const int n0 = blockIdx.x * 128;
    const int m0 = blockIdx.y * 128;

    f32x4 acc[4][4];
#pragma unroll
    for (int i = 0; i < 4; ++i)
#pragma unroll
        for (int j = 0; j < 4; ++j) acc[i][j] = (f32x4)0.0f;

    const int a_g = tid & 7;
    const int a_rb = tid >> 3;
    const int aswz = lr & 6;

    for (int kt = 0; kt < K_DIM / 64; ++kt) {
        const int k0 = kt * 64;
#pragma unroll
        for (int o = 0; o < 4; ++o) {
            const int row = o * 32 + a_rb;
            const float* ap = A + (size_t)(m0 + row) * K_DIM + k0 + a_g * 8;
            const f32x4 v0 = *(const f32x4*)ap;
            const f32x4 v1 = *(const f32x4*)(ap + 4);
            u32x2 r;
            r.x = cvt4(v0[0], v0[1], v0[2], v0[3]);
            r.y = cvt4(v1[0], v1[1], v1[2], v1[3]);
            *(u32x2*)(sA + row * 64 + ((a_g ^ (row & 6)) * 8)) = r;
        }
#pragma unroll
        for (int o = 0; o < 4; ++o) {
            const int e = o * 256 + tid;
            const int g = e >> 7;
            const int n = e & 127;
            const float* wp = W + (size_t)(k0 + g * 8) * N_DIM + n0 + n;
            float f[8];
#pragma unroll
            for (int j = 0; j < 8; ++j) f[j] = wp[(size_t)j * N_DIM];
            u32x2 r;
            r.x = cvt4(f[0], f[1], f[2], f[3]);
            r.y = cvt4(f[4], f[5], f[6], f[7]);
            *(u32x2*)(sB + g * 1024 + n * 8) = r;
        }
        __syncthreads();

#pragma unroll
        for (int kk = 0; kk < 2; ++kk) {
            long long af[4], bfr[4];
            const int gread = kk * 4 + lg;
#pragma unroll
            for (int mi = 0; mi < 4; ++mi) {
                const int m = wr * 64 + mi * 16 + lr;
                af[mi] = *(const long long*)(sA + m * 64 + ((gread ^ aswz) * 8));
            }
#pragma unroll
            for (int nj = 0; nj < 4; ++nj) {
                const int n = wc * 64 + nj * 16 + lr;
                bfr[nj] = *(const long long*)(sB + gread * 1024 + n * 8);
            }
#pragma unroll
            for (int mi = 0; mi < 4; ++mi)
#pragma unroll
                for (int nj = 0; nj < 4; ++nj)
                    acc[mi][nj] = __builtin_amdgcn_mfma_f32_16x16x32_fp8_fp8(
                        af[mi], bfr[nj], acc[mi][nj], 0, 0, 0);
        }
        __syncthreads();
    }

#pragma unroll
    for (int nj = 0; nj < 4; ++nj) {
        const int col = n0 + wc * 64 + nj * 16 + lr;
        const float sc = scale_b[col];
#pragma unroll
        for (int mi = 0; mi < 4; ++mi) {
            const int row = m0 + wr * 64 + mi * 16 + lg * 4;
#pragma unroll
            for (int r = 0; r < 4; ++r) {
                const float v = acc[mi][nj][r] * sc;
                out[(size_t)(row + r) * N_DIM + col] = (float)(_Float16)v;
            }
        }
    }
}

extern "C" void kernel_launch(void* const* d_in, const int* in_sizes, int n_in,
                              void* d_out, int out_size, void* d_ws, size_t ws_size,
                              hipStream_t stream) {
    (void)out_size;
    const void* pA = d_in[0];
    const void* pW = (n_in > 1) ? d_in[1] : d_in[0];
    const void* pS = (n_in > 2) ? d_in[2] : d_in[0];
    for (int i = 0; i < n_in && i < 3; ++i) {
        if (in_sizes[i] == M_DIM * K_DIM) pA = d_in[i];
        else if (in_sizes[i] == K_DIM * N_DIM) pW = d_in[i];
        else if (in_sizes[i] == N_DIM) pS = d_in[i];
    }
    const float* A = (const float*)pA;
    const float* W = (const float*)pW;
    const float* sb = (const float*)pS;
    float* out = (float*)d_out;

    if (ws_size >= WS_NEEDED && d_ws != nullptr) {
        unsigned char* A8 = (unsigned char*)d_ws;
        unsigned char* W8 = A8 + (size_t)M_DIM * K_DIM;
        quant_a_kernel<<<2048, 256, 0, stream>>>(A, A8);
        quant_w_kernel<<<256, 256, 0, stream>>>(W, W8);
        gemm_fp8_kernel<<<(M_DIM / BM) * (N_DIM / BN), 256, 0, stream>>>(A8, W8, sb, out);
    } else {
        gemm_fused_kernel<<<dim3(N_DIM / 128, M_DIM / 128), 256, 0, stream>>>(A, W, sb, out);
    }
}